// Round 4
// baseline (1891.341 us; speedup 1.0000x reference)
//
#include <hip/hip_runtime.h>

#define DEV __device__ __forceinline__

typedef __attribute__((ext_vector_type(8))) short short8;
typedef __attribute__((ext_vector_type(4))) float f32x4;

DEV float fast_rcp(float x) { return __builtin_amdgcn_rcpf(x); }
DEV float sigm(float x) { return fast_rcp(1.0f + __expf(-x)); }
DEV float tanhf_fast(float x) { return 1.0f - 2.0f * fast_rcp(1.0f + __expf(2.0f * x)); }

DEV short f2bf(float f) {
    unsigned u = __float_as_uint(f);
    return (short)((u + 0x7FFFu + ((u >> 16) & 1u)) >> 16);
}

// ---------------------------------------------------------------------------
// prep: zero epilogue counters, L_w -> bf16, prenet_in -> res[:, :128]
// grid(64) x 256
// ---------------------------------------------------------------------------
__global__ void prep_kernel(const float* __restrict__ Lw, short* __restrict__ lwbf,
                            const float* __restrict__ pre, float* __restrict__ res,
                            int* __restrict__ ctr)
{
    int i = blockIdx.x * 256 + threadIdx.x;   // < 16384
    if (i < 512) ctr[i] = 0;
    if (i < 8192) lwbf[i] = f2bf(Lw[i]);
    int m = i >> 7, d = i & 127;
    res[m * 640 + d] = pre[i];
}

// ---------------------------------------------------------------------------
// Split-K bf16-MFMA GEMM with fused epilogue (decoupled last-arriver).
// Partial[chunk][m][n] = A[m,k-range]·W[n,k-range]  (A,W fp32, cast bf16).
// M=128, n-tile 32, K1 % 32 == 0, KC % 32 == 0, all lda/ldw % 4 == 0.
// Grid = (N/32)*KS blocks, 256 threads (4 waves; wave w: m in [32w,32w+32)).
// mode: 0 = partials only; 1 = reduce+bias(+tanh if act); 2 = LSTM gate (H);
//       3 = GRU gate (adds gi partials).
// ---------------------------------------------------------------------------
__global__ __launch_bounds__(256) void mfma_gemm(
    const float* __restrict__ A1, int K1, const float* __restrict__ W1, int ldw1,
    const float* __restrict__ A2, int K2, const float* __restrict__ W2, int ldw2,
    float* __restrict__ Cp, int N, int KS, int KC,
    int mode, int H, int act,
    const float* __restrict__ b1, const float* __restrict__ b2,
    const float* __restrict__ c_in, float* __restrict__ h_out, float* __restrict__ c_out,
    float* __restrict__ xacc, float* __restrict__ xmir,
    const float* __restrict__ gi_p, int KS_gi, const float* __restrict__ h_prev,
    int* __restrict__ ctr)
{
    __shared__ short As[2][128][32];
    __shared__ short Ws[2][32][32];
    __shared__ int lastf;

    const int tid = threadIdx.x;
    const int chunk = blockIdx.x % KS;
    const int j = blockIdx.x / KS;
    const int n0 = j * 32;
    const int kbeg = chunk * KC, nsteps = KC / 32;

    const int am = tid >> 1, ak = (tid & 1) * 16;
    const int wn = tid >> 3, wk = (tid & 7) * 4;

    float4 ar0, ar1, ar2, ar3, wr;
    auto load = [&](int k0) {
        const float* A; const float* W; int lda, ldw, kc;
        if (k0 < K1) { A = A1; W = W1; lda = K1; ldw = ldw1; kc = k0; }
        else         { A = A2; W = W2; lda = K2; ldw = ldw2; kc = k0 - K1; }
        const float* ap = A + (size_t)am * lda + kc + ak;
        ar0 = ((const float4*)ap)[0]; ar1 = ((const float4*)ap)[1];
        ar2 = ((const float4*)ap)[2]; ar3 = ((const float4*)ap)[3];
        wr = *(const float4*)(W + (size_t)(n0 + wn) * ldw + kc + wk);
    };
    auto stos = [&](int buf) {
        short* arow = &As[buf][am][ak];
        arow[0] = f2bf(ar0.x); arow[1] = f2bf(ar0.y); arow[2]  = f2bf(ar0.z); arow[3]  = f2bf(ar0.w);
        arow[4] = f2bf(ar1.x); arow[5] = f2bf(ar1.y); arow[6]  = f2bf(ar1.z); arow[7]  = f2bf(ar1.w);
        arow[8] = f2bf(ar2.x); arow[9] = f2bf(ar2.y); arow[10] = f2bf(ar2.z); arow[11] = f2bf(ar2.w);
        arow[12] = f2bf(ar3.x); arow[13] = f2bf(ar3.y); arow[14] = f2bf(ar3.z); arow[15] = f2bf(ar3.w);
        short* wrow = &Ws[buf][wn][wk];
        wrow[0] = f2bf(wr.x); wrow[1] = f2bf(wr.y); wrow[2] = f2bf(wr.z); wrow[3] = f2bf(wr.w);
    };

    const int lane = tid & 63, wv = tid >> 6, q = lane >> 4, r16 = lane & 15;
    f32x4 acc00 = {0.f, 0.f, 0.f, 0.f}, acc01 = acc00, acc10 = acc00, acc11 = acc00;

    load(kbeg); stos(0); __syncthreads();
    for (int it = 0; it < nsteps; ++it) {
        const int cur = it & 1;
        if (it + 1 < nsteps) load(kbeg + (it + 1) * 32);
        short8 a0 = *(const short8*)&As[cur][32 * wv + r16][q * 8];
        short8 a1 = *(const short8*)&As[cur][32 * wv + 16 + r16][q * 8];
        short8 b0 = *(const short8*)&Ws[cur][r16][q * 8];
        short8 b1f = *(const short8*)&Ws[cur][16 + r16][q * 8];
        acc00 = __builtin_amdgcn_mfma_f32_16x16x32_bf16(a0, b0, acc00, 0, 0, 0);
        acc01 = __builtin_amdgcn_mfma_f32_16x16x32_bf16(a0, b1f, acc01, 0, 0, 0);
        acc10 = __builtin_amdgcn_mfma_f32_16x16x32_bf16(a1, b0, acc10, 0, 0, 0);
        acc11 = __builtin_amdgcn_mfma_f32_16x16x32_bf16(a1, b1f, acc11, 0, 0, 0);
        if (it + 1 < nsteps) stos(cur ^ 1);
        __syncthreads();
    }

    // partial store: D row = 4q+r (m), col = r16 (n)
    {
        float* Co = Cp + (size_t)chunk * 128 * N;
        const int mb = 32 * wv + 4 * q;
#pragma unroll
        for (int r = 0; r < 4; ++r) {
            Co[(size_t)(mb + r) * N + n0 + r16]           = acc00[r];
            Co[(size_t)(mb + r) * N + n0 + 16 + r16]      = acc01[r];
            Co[(size_t)(mb + 16 + r) * N + n0 + r16]      = acc10[r];
            Co[(size_t)(mb + 16 + r) * N + n0 + 16 + r16] = acc11[r];
        }
    }
    if (mode == 0) return;

    __syncthreads();        // all partial stores vmcnt-complete per wave
    __threadfence();        // publish to device scope
    int grp, tot;
    if (mode == 1)      { grp = j;            tot = KS; }
    else if (mode == 2) { grp = j % (H / 32); tot = 4 * KS; }
    else                { grp = j % 8;        tot = 3 * KS; }
    if (tid == 0) lastf = (atomicAdd(&ctr[grp], 1) == tot - 1);
    __syncthreads();
    if (!lastf) return;
    __threadfence();        // acquire: invalidate stale cached lines

    const int col = grp * 32 + (tid & 31);
    const int mb2 = (tid >> 5) * 16;

    if (mode == 1) {
#pragma unroll 4
        for (int i = 0; i < 16; ++i) {
            int m = mb2 + i;
            float v = b1[col];
            for (int s = 0; s < KS; ++s) v += Cp[(size_t)s * 128 * N + (size_t)m * N + col];
            if (act) v = tanhf_fast(v);
            h_out[(size_t)m * N + col] = v;
        }
    } else if (mode == 2) {
        for (int i = 0; i < 16; ++i) {
            int m = mb2 + i;
            size_t base = (size_t)m * N + col;
            float iv = b1[col] + b2[col];
            float fv = b1[H + col] + b2[H + col];
            float gv = b1[2 * H + col] + b2[2 * H + col];
            float ov = b1[3 * H + col] + b2[3 * H + col];
            for (int s = 0; s < KS; ++s) {
                const float* p = Cp + (size_t)s * 128 * N + base;
                iv += p[0]; fv += p[H]; gv += p[2 * H]; ov += p[3 * H];
            }
            float c2 = sigm(fv) * c_in[(size_t)m * H + col] + sigm(iv) * tanhf_fast(gv);
            float h2 = sigm(ov) * tanhf_fast(c2);
            h_out[(size_t)m * H + col] = h2;
            c_out[(size_t)m * H + col] = c2;
            if (xacc) {
                float xv = xacc[(size_t)m * H + col] + h2;
                xacc[(size_t)m * H + col] = xv;
                if (xmir) xmir[(size_t)m * 640 + 128 + col] = xv;
            }
        }
    } else {  // GRU: N = 768
        for (int i = 0; i < 16; ++i) {
            int m = mb2 + i;
            size_t base = (size_t)m * 768 + col;
            float ir = b1[col], iz = b1[256 + col], in = b1[512 + col];
            for (int s = 0; s < KS_gi; ++s) {
                const float* p = gi_p + (size_t)s * 128 * 768 + base;
                ir += p[0]; iz += p[256]; in += p[512];
            }
            float hr = b2[col], hz = b2[256 + col], hn = b2[512 + col];
            for (int s = 0; s < KS; ++s) {
                const float* p = Cp + (size_t)s * 128 * 768 + base;
                hr += p[0]; hz += p[256]; hn += p[512];
            }
            float r = sigm(ir + hr), z = sigm(iz + hz);
            float n = tanhf_fast(in + r * hn);
            h_out[m * 256 + col] = (1.f - z) * n + z * h_prev[m * 256 + col];
        }
    }
}

// ---------------------------------------------------------------------------
// Fused LSA u-kernel + softmax-normalization epilogue.
// grid(B*16) blocks (64 t's each), 256 threads.
// ---------------------------------------------------------------------------
__global__ __launch_bounds__(256) void attn_u_kernel(
    const float* __restrict__ esp, const float* __restrict__ pq,
    const short* __restrict__ LwBf, const float* __restrict__ Lb,
    const float* __restrict__ vw, const float* __restrict__ cw,
    const float* __restrict__ cum, const float* __restrict__ prev,
    float* __restrict__ sig_out,
    float* __restrict__ scores, float* __restrict__ cum_new, float* __restrict__ ctx,
    int* __restrict__ ctr)
{
    const int b = blockIdx.x >> 4;
    const int t0 = (blockIdx.x & 15) << 6;
    const int tid = threadIdx.x;

    __shared__ float cum_s[94], prev_s[94];
    __shared__ float cw_s[2][32][33];
    __shared__ short conv_bf[64 * 32];
    __shared__ short lw_bf[256 * 32];
    __shared__ float pq_s[256], vw_s[256];
    __shared__ int lastf;
    __shared__ float red[4];

    if (tid < 94) {
        int ti = t0 - 15 + tid;
        cum_s[tid] = (ti >= 0 && ti < 1024) ? cum[b * 1024 + ti] : 0.f;
    } else if (tid >= 128 && tid < 222) {
        int i = tid - 128;
        int ti = t0 - 15 + i;
        prev_s[i] = (ti >= 0 && ti < 1024) ? prev[b * 1024 + ti] : 0.f;
    }
    for (int i = tid; i < 2048; i += 256) {
        int which = i >> 10, c = (i >> 5) & 31, k = i & 31;
        cw_s[which][c][k] = (k < 31) ? cw[(c * 2 + which) * 31 + k] : 0.f;
    }
    {
        const int4* src = (const int4*)LwBf;
        int4* dst = (int4*)lw_bf;
#pragma unroll
        for (int k = 0; k < 4; ++k) dst[tid + k * 256] = src[tid + k * 256];
    }
    pq_s[tid] = pq[b * 256 + tid] + Lb[tid];
    vw_s[tid] = vw[tid];
    __syncthreads();

    {
        int c = tid & 31, t8 = (tid >> 5) << 3;
        float a[8] = {0.f, 0.f, 0.f, 0.f, 0.f, 0.f, 0.f, 0.f};
        for (int k = 0; k < 31; ++k) {
            float w0 = cw_s[0][c][k], w1 = cw_s[1][c][k];
#pragma unroll
            for (int jj = 0; jj < 8; ++jj)
                a[jj] += w0 * cum_s[t8 + jj + k] + w1 * prev_s[t8 + jj + k];
        }
#pragma unroll
        for (int jj = 0; jj < 8; ++jj) conv_bf[(t8 + jj) * 32 + c] = f2bf(a[jj]);
    }
    __syncthreads();

    const int lane = tid & 63, w = tid >> 6;
    const int q = lane >> 4, c16 = lane & 15;
    const int myt = t0 + w * 16 + c16;

    short8 bfrag = *(const short8*)&conv_bf[(w * 16 + c16) * 32 + q * 8];
    const float* er = esp + ((size_t)(b * 1024 + myt) << 8);

    float s = 0.f;
#pragma unroll
    for (int dt = 0; dt < 16; ++dt) {
        short8 afrag = *(const short8*)&lw_bf[(dt * 16 + c16) * 32 + q * 8];
        f32x4 acc = {0.f, 0.f, 0.f, 0.f};
        acc = __builtin_amdgcn_mfma_f32_16x16x32_bf16(afrag, bfrag, acc, 0, 0, 0);
        const int d0 = dt * 16 + q * 4;
        float4 e   = *(const float4*)(er + d0);
        float4 pqv = *(const float4*)&pq_s[d0];
        float4 vwv = *(const float4*)&vw_s[d0];
        s += tanhf_fast(pqv.x + e.x + acc[0]) * vwv.x;
        s += tanhf_fast(pqv.y + e.y + acc[1]) * vwv.y;
        s += tanhf_fast(pqv.z + e.z + acc[2]) * vwv.z;
        s += tanhf_fast(pqv.w + e.w + acc[3]) * vwv.w;
    }
    s += __shfl_xor(s, 16);
    s += __shfl_xor(s, 32);
    if (lane < 16)
        sig_out[b * 1024 + t0 + w * 16 + lane] = sigm(s);

    // ---- normalization epilogue (last of the 16 blocks for this b) ----
    __syncthreads();
    __threadfence();
    if (tid == 0) lastf = (atomicAdd(&ctr[b], 1) == 15);
    __syncthreads();
    if (!lastf) return;
    __threadfence();

    float4 sv = *(const float4*)&sig_out[b * 1024 + tid * 4];
    float s2 = sv.x + sv.y + sv.z + sv.w;
#pragma unroll
    for (int off = 1; off < 64; off <<= 1) s2 += __shfl_xor(s2, off);
    if ((tid & 63) == 0) red[tid >> 6] = s2;
    __syncthreads();
    float inv = fast_rcp(red[0] + red[1] + red[2] + red[3]);
    float4 cv = *(const float4*)&cum[b * 1024 + tid * 4];
    float4 sc = {sv.x * inv, sv.y * inv, sv.z * inv, sv.w * inv};
    *(float4*)&scores[b * 1024 + tid * 4] = sc;
    float4 cn = {cv.x + sc.x, cv.y + sc.y, cv.z + sc.z, cv.w + sc.w};
    *(float4*)&cum_new[b * 1024 + tid * 4] = cn;
    ctx[b * 256 + tid] = 0.f;
}

// ---------------------------------------------------------------------------
// context[b,d] = sum_t scores[b,t] * es[b,t,d];  grid(B*8) t-chunks of 128.
// ---------------------------------------------------------------------------
__global__ void attn_ctx_kernel(const float* __restrict__ scores, const float* __restrict__ es,
                                float* __restrict__ ctx)
{
    __shared__ float sc_s[128];
    int b = blockIdx.x >> 3;
    int tbase = (blockIdx.x & 7) * 128;
    int tid = threadIdx.x;
    if (tid < 128) sc_s[tid] = scores[b * 1024 + tbase + tid];
    __syncthreads();
    float a = 0.f;
    const float* ep = es + ((size_t)(b * 1024 + tbase)) * 256 + tid;
#pragma unroll 4
    for (int tt = 0; tt < 128; ++tt)
        a += sc_s[tt] * ep[(size_t)tt * 256];
    atomicAdd(&ctx[b * 256 + tid], a);
}

// ---------------------------------------------------------------------------
// cond copy + stop projection.  grid(128) x 64.
// ---------------------------------------------------------------------------
__global__ void stop_cond_kernel(const float* __restrict__ res, const float* __restrict__ sw,
                                 const float* __restrict__ sb, float* __restrict__ cond,
                                 float* __restrict__ stop)
{
    int m = blockIdx.x, lane = threadIdx.x;
    float s = 0.f;
    for (int k = lane; k < 640; k += 64) {
        float v = res[m * 640 + k];
        cond[m * 640 + k] = v;
        s += v * sw[k];
    }
#pragma unroll
    for (int off = 1; off < 64; off <<= 1) s += __shfl_xor(s, off);
    if (lane == 0) stop[m] = sigm(s + sb[0]);
}

// ---------------------------------------------------------------------------
extern "C" void kernel_launch(void* const* d_in, const int* in_sizes, int n_in,
                              void* d_out, int out_size, void* d_ws, size_t ws_size,
                              hipStream_t stream)
{
    const float* encoder_seq      = (const float*)d_in[0];
    const float* encoder_seq_proj = (const float*)d_in[1];
    const float* prenet_in        = (const float*)d_in[2];
    const float* attn_hidden      = (const float*)d_in[3];
    const float* rnn1_h  = (const float*)d_in[4];
    const float* rnn1_c  = (const float*)d_in[5];
    const float* rnn2_h  = (const float*)d_in[6];
    const float* rnn2_c  = (const float*)d_in[7];
    const float* res_h   = (const float*)d_in[8];
    const float* res_c   = (const float*)d_in[9];
    const float* context_vec = (const float*)d_in[10];
    const float* cumulative  = (const float*)d_in[11];
    const float* attn_prev   = (const float*)d_in[12];
    const float* fc1_w = (const float*)d_in[13];
    const float* fc1_b = (const float*)d_in[14];
    const float* fc2_w = (const float*)d_in[15];
    const float* fc2_b = (const float*)d_in[16];
    const float* gru_wih = (const float*)d_in[17];
    const float* gru_whh = (const float*)d_in[18];
    const float* gru_bih = (const float*)d_in[19];
    const float* gru_bhh = (const float*)d_in[20];
    const float* conv_w = (const float*)d_in[21];
    const float* L_w = (const float*)d_in[22];
    const float* L_b = (const float*)d_in[23];
    const float* W_w = (const float*)d_in[24];
    const float* W_b = (const float*)d_in[25];
    const float* v_w = (const float*)d_in[26];
    const float* ri_w = (const float*)d_in[27];
    const float* ri_b = (const float*)d_in[28];
    const float* r1_wih = (const float*)d_in[29];
    const float* r1_whh = (const float*)d_in[30];
    const float* r1_bih = (const float*)d_in[31];
    const float* r1_bhh = (const float*)d_in[32];
    const float* r2_wih = (const float*)d_in[33];
    const float* r2_whh = (const float*)d_in[34];
    const float* r2_bih = (const float*)d_in[35];
    const float* r2_bhh = (const float*)d_in[36];
    const float* res_wih = (const float*)d_in[37];
    const float* res_whh = (const float*)d_in[38];
    const float* res_bih = (const float*)d_in[39];
    const float* res_bhh = (const float*)d_in[40];
    const float* stop_w = (const float*)d_in[41];
    const float* stop_b = (const float*)d_in[42];

    float* ws  = (float*)d_ws;
    float* out = (float*)d_out;

    // workspace offsets (floats)
    const size_t OFF_P    = 0;         // [128,256]
    const size_t OFF_POUT = 32768;     // [128,128]
    const size_t OFF_PQ   = 49152;     // [128,256]
    const size_t OFF_SIG  = 81920;     // [128,1024]
    const size_t OFF_X    = 212992;    // [128,512]
    const size_t OFF_RES  = 278528;    // [128,640]
    const size_t OFF_LWT  = 360448;    // bf16 L_w (8192 shorts)
    const size_t OFF_CTR  = 364544;    // 512 ints
    const size_t OFF_PART = 365056;    // KS*128*2560 fp32 max (10.5 MB)
    const size_t OFF_PARTB = OFF_PART + (size_t)8 * 128 * 2560;  // gi partials (12*128*768)

    // output offsets (floats)
    const size_t O_COND   = 0;
    const size_t O_STOP   = 81920;
    const size_t O_SCORES = 82048;
    const size_t O_ATTNH  = 213120;
    const size_t O_H1     = 245888;
    const size_t O_C1     = 311424;
    const size_t O_H2     = 376960;
    const size_t O_C2     = 442496;
    const size_t O_HS     = 508032;
    const size_t O_CS     = 835712;
    const size_t O_CTX    = 1163392;
    const size_t O_CUM    = 1196160;

    short* lwbf = (short*)(ws + OFF_LWT);
    int* ctr = (int*)(ws + OFF_CTR);
    float* PART = ws + OFF_PART;
    float* PARTB = ws + OFF_PARTB;

    // counters: fc1=0, fc2=8, gh=16, pq=32, ri=48, r1=64, r2=96, res_i=128+32i, attn=256..383
    prep_kernel<<<64, 256, 0, stream>>>(L_w, lwbf, prenet_in, ws + OFF_RES, ctr);

    // PreNet fc1: N=256, K=128, KS=4 (KC=32) -> tanh -> P
    mfma_gemm<<<8 * 4, 256, 0, stream>>>(prenet_in, 128, fc1_w, 128, nullptr, 0, nullptr, 0,
                                         PART, 256, 4, 32, 1, 0, 1, fc1_b, nullptr,
                                         nullptr, ws + OFF_P, nullptr, nullptr, nullptr,
                                         nullptr, 0, nullptr, ctr + 0);
    // PreNet fc2: N=128, K=256, KS=8 (KC=32) -> tanh -> POUT
    mfma_gemm<<<4 * 8, 256, 0, stream>>>(ws + OFF_P, 256, fc2_w, 256, nullptr, 0, nullptr, 0,
                                         PART, 128, 8, 32, 1, 0, 1, fc2_b, nullptr,
                                         nullptr, ws + OFF_POUT, nullptr, nullptr, nullptr,
                                         nullptr, 0, nullptr, ctr + 8);
    // GRU gi: N=768, K=256+128, KS=12 (KC=32), partials only -> PARTB
    mfma_gemm<<<24 * 12, 256, 0, stream>>>(context_vec, 256, gru_wih, 384,
                                           ws + OFF_POUT, 128, gru_wih + 256, 384,
                                           PARTB, 768, 12, 32, 0, 0, 0, nullptr, nullptr,
                                           nullptr, nullptr, nullptr, nullptr, nullptr,
                                           nullptr, 0, nullptr, nullptr);
    // GRU gh: N=768, K=256, KS=8 (KC=32) + GRU-gate epilogue -> attn_h
    mfma_gemm<<<24 * 8, 256, 0, stream>>>(attn_hidden, 256, gru_whh, 256, nullptr, 0, nullptr, 0,
                                          PART, 768, 8, 32, 3, 0, 0, gru_bih, gru_bhh,
                                          nullptr, out + O_ATTNH, nullptr, nullptr, nullptr,
                                          PARTB, 12, attn_hidden, ctr + 16);
    // pq: N=256, K=256, KS=8 -> + W_b -> PQ
    mfma_gemm<<<8 * 8, 256, 0, stream>>>(out + O_ATTNH, 256, W_w, 256, nullptr, 0, nullptr, 0,
                                         PART, 256, 8, 32, 1, 0, 0, W_b, nullptr,
                                         nullptr, ws + OFF_PQ, nullptr, nullptr, nullptr,
                                         nullptr, 0, nullptr, ctr + 32);
    // attention u + fused normalization
    attn_u_kernel<<<2048, 256, 0, stream>>>(encoder_seq_proj, ws + OFF_PQ, lwbf,
                                            L_b, v_w, conv_w, cumulative, attn_prev,
                                            ws + OFF_SIG, out + O_SCORES, out + O_CUM,
                                            out + O_CTX, ctr + 256);
    attn_ctx_kernel<<<1024, 256, 0, stream>>>(out + O_SCORES, encoder_seq, out + O_CTX);

    // ri: N=512, K=512 (2-seg), KS=8 (KC=64) -> X
    mfma_gemm<<<16 * 8, 256, 0, stream>>>(out + O_CTX, 256, ri_w, 512,
                                          out + O_ATTNH, 256, ri_w + 256, 512,
                                          PART, 512, 8, 64, 1, 0, 0, ri_b, nullptr,
                                          nullptr, ws + OFF_X, nullptr, nullptr, nullptr,
                                          nullptr, 0, nullptr, ctr + 48);
    // LSTM1: N=2048, K=1024, KS=8 (KC=128) + gate -> h1,c1, X+=h1
    mfma_gemm<<<64 * 8, 256, 0, stream>>>(ws + OFF_X, 512, r1_wih, 512,
                                          rnn1_h, 512, r1_whh, 512,
                                          PART, 2048, 8, 128, 2, 512, 0, r1_bih, r1_bhh,
                                          rnn1_c, out + O_H1, out + O_C1,
                                          ws + OFF_X, nullptr,
                                          nullptr, 0, nullptr, ctr + 64);
    // LSTM2 + gate -> h2,c2, X+=h2, res[:,128:640]=X
    mfma_gemm<<<64 * 8, 256, 0, stream>>>(ws + OFF_X, 512, r2_wih, 512,
                                          rnn2_h, 512, r2_whh, 512,
                                          PART, 2048, 8, 128, 2, 512, 0, r2_bih, r2_bhh,
                                          rnn2_c, out + O_H2, out + O_C2,
                                          ws + OFF_X, ws + OFF_RES,
                                          nullptr, 0, nullptr, ctr + 96);
    // Residual stack: N=2560, K=640(x2 seg as one), KS=8 (KC=160) + gate
    for (int i = 0; i < 4; ++i) {
        mfma_gemm<<<80 * 8, 256, 0, stream>>>(ws + OFF_RES, 640,
                                              res_wih + (size_t)i * 2560 * 640, 640,
                                              res_h + (size_t)i * 81920, 640,
                                              res_whh + (size_t)i * 2560 * 640, 640,
                                              PART, 2560, 8, 160, 2, 640, 0,
                                              res_bih + (size_t)i * 2560,
                                              res_bhh + (size_t)i * 2560,
                                              res_c + (size_t)i * 81920,
                                              out + O_HS + (size_t)i * 81920,
                                              out + O_CS + (size_t)i * 81920,
                                              ws + OFF_RES, nullptr,
                                              nullptr, 0, nullptr, ctr + 128 + 32 * i);
    }

    stop_cond_kernel<<<128, 64, 0, stream>>>(ws + OFF_RES, stop_w, stop_b,
                                             out + O_COND, out + O_STOP);
}